// Round 12
// baseline (300.464 us; speedup 1.0000x reference)
//
#include <hip/hip_runtime.h>
#include <math.h>

#define BS  2048
#define SEQ 200
#define DIM 64
#define C1  32
#define C2  16

typedef __attribute__((ext_vector_type(8))) short bf16x8_t;
typedef __attribute__((ext_vector_type(4))) float f32x4_t;

__device__ __forceinline__ float dice1(float x, float m, float r, float al) {
    float t = (x - m) * r;
    float p = 1.f / (1.f + __expf(-t));
    return x * (al + p * (1.f - al));
}

__device__ __forceinline__ unsigned short f2bf(float f) {
    union { float f; unsigned u; } a;
    a.f = f;
    unsigned r = a.u + 0x7fff + ((a.u >> 16) & 1);   // RNE
    return (unsigned short)(r >> 16);
}

__device__ __forceinline__ float bf2f(short h) {
    union { unsigned u; float f; } a;
    a.u = ((unsigned)(unsigned short)h) << 16;
    return a.f;
}

// ---------------------------------------------------------------------------
// k1: gemm1 via bf16 MFMA (identical to the twice-validated round-7 kernel).
// ---------------------------------------------------------------------------
__global__ __launch_bounds__(256) void k_gemm1(const float* __restrict__ q,
                                               const float* __restrict__ ub,
                                               const float* __restrict__ W1,
                                               const float* __restrict__ b1,
                                               short* __restrict__ z1) {
    const int bs = blockIdx.x;
    const int tid = threadIdx.x;
    __shared__ __align__(16) short s_B[2 * 2 * 64 * 8];   // 4 KB, frag order
    __shared__ __align__(16) float s_qw[C1];
    __shared__ __align__(16) short s_z[208 * C1];         // 13.3 KB repack buf

    const float* qrow = q + bs * DIM;

    {
        const int kt = tid >> 7;
        const int nt = (tid >> 6) & 1;
        const int l  = tid & 63;
        const int c  = nt * 16 + (l & 15);
        bf16x8_t bfr;
        #pragma unroll
        for (int j = 0; j < 8; ++j) {
            int k = kt * 32 + ((l >> 4) << 3) + j;
            float wb = W1[(64 + k) * C1 + c] - W1[(128 + k) * C1 + c]
                     + qrow[k] * W1[(192 + k) * C1 + c];
            bfr[j] = (short)f2bf(wb);
        }
        *(bf16x8_t*)((char*)s_B + (((kt * 2 + nt) * 64) + l) * 16) = bfr;
    }
    if (tid < C1) {
        float a = b1[tid];
        #pragma unroll 8
        for (int d = 0; d < DIM; ++d)
            a = fmaf(qrow[d], W1[d * C1 + tid] + W1[(128 + d) * C1 + tid], a);
        s_qw[tid] = a;
    }
    __syncthreads();

    const int wave = tid >> 6;
    const int l = tid & 63;
    const int g = l >> 4;
    const bf16x8_t b00 = *(const bf16x8_t*)((char*)s_B + (0 * 64 + l) * 16);
    const bf16x8_t b01 = *(const bf16x8_t*)((char*)s_B + (1 * 64 + l) * 16);
    const bf16x8_t b10 = *(const bf16x8_t*)((char*)s_B + (2 * 64 + l) * 16);
    const bf16x8_t b11 = *(const bf16x8_t*)((char*)s_B + (3 * 64 + l) * 16);
    const float qw0 = s_qw[l & 15];
    const float qw1 = s_qw[16 + (l & 15)];
    const float* ubb = ub + (size_t)bs * SEQ * DIM;

    for (int mt = wave; mt < 13; mt += 4) {
        int row = mt * 16 + (l & 15);
        int rc = row > SEQ - 1 ? SEQ - 1 : row;
        const float* rp = ubb + rc * DIM + g * 8;
        float4 f0 = *(const float4*)(rp);
        float4 f1 = *(const float4*)(rp + 4);
        float4 f2 = *(const float4*)(rp + 32);
        float4 f3 = *(const float4*)(rp + 36);
        bf16x8_t a0, a1;
        a0[0] = (short)f2bf(f0.x); a0[1] = (short)f2bf(f0.y);
        a0[2] = (short)f2bf(f0.z); a0[3] = (short)f2bf(f0.w);
        a0[4] = (short)f2bf(f1.x); a0[5] = (short)f2bf(f1.y);
        a0[6] = (short)f2bf(f1.z); a0[7] = (short)f2bf(f1.w);
        a1[0] = (short)f2bf(f2.x); a1[1] = (short)f2bf(f2.y);
        a1[2] = (short)f2bf(f2.z); a1[3] = (short)f2bf(f2.w);
        a1[4] = (short)f2bf(f3.x); a1[5] = (short)f2bf(f3.y);
        a1[6] = (short)f2bf(f3.z); a1[7] = (short)f2bf(f3.w);
        f32x4_t acc0 = {0.f, 0.f, 0.f, 0.f};
        f32x4_t acc1 = {0.f, 0.f, 0.f, 0.f};
        acc0 = __builtin_amdgcn_mfma_f32_16x16x32_bf16(a0, b00, acc0, 0, 0, 0);
        acc0 = __builtin_amdgcn_mfma_f32_16x16x32_bf16(a1, b10, acc0, 0, 0, 0);
        acc1 = __builtin_amdgcn_mfma_f32_16x16x32_bf16(a0, b01, acc1, 0, 0, 0);
        acc1 = __builtin_amdgcn_mfma_f32_16x16x32_bf16(a1, b11, acc1, 0, 0, 0);
        const int orow = mt * 16 + g * 4;
        #pragma unroll
        for (int r = 0; r < 4; ++r) {
            s_z[(orow + r) * C1 + (l & 15)]      = (short)f2bf(acc0[r] + qw0);
            s_z[(orow + r) * C1 + 16 + (l & 15)] = (short)f2bf(acc1[r] + qw1);
        }
    }
    __syncthreads();
    bf16x8_t* dst = (bf16x8_t*)(z1 + (size_t)bs * SEQ * C1);
    const bf16x8_t* srcl = (const bf16x8_t*)s_z;
    for (int i = tid; i < SEQ * C1 / 8; i += 256) dst[i] = srcl[i];
}

// ---------------------------------------------------------------------------
// k2: fused stats1 (redundant per strip, z1 is L3-resident) + dice1 +
// gemm2 MFMA + atomic stats2 accumulation. Grid (25 strips, 8 parts).
// ---------------------------------------------------------------------------
__global__ __launch_bounds__(256) void k_mlp2(const short* __restrict__ z1,
                                              const float* __restrict__ alpha1,
                                              const float* __restrict__ W2,
                                              const float* __restrict__ b2,
                                              short* __restrict__ z2,
                                              float* __restrict__ aS2,
                                              float* __restrict__ aQ2) {
    const int strip = blockIdx.x;   // 8 seqs
    const int part = blockIdx.y;    // 256 bs
    const int tid = threadIdx.x;
    const int wave = tid >> 6;
    const int l = tid & 63;
    __shared__ float s_mu[8][C1];
    __shared__ float s_rs[8][C1];
    __shared__ float redS[4][4][8], redQ[4][4][8];

    // ---- Phase A: stats1 over ALL 2048 batch rows for this strip's 8 seqs ----
    {
        const int cq = tid & 3;     // 4 channel quads of 8
        const int rg = tid >> 2;    // 64 row groups
        for (int ss = 0; ss < 8; ++ss) {
            const int seqg = strip * 8 + ss;
            float s[8], qq[8];
            #pragma unroll
            for (int j = 0; j < 8; ++j) { s[j] = 0.f; qq[j] = 0.f; }
            for (int it = 0; it < BS / 64; ++it) {
                int b = rg + it * 64;
                bf16x8_t v = *(const bf16x8_t*)(z1 + ((size_t)b * SEQ + seqg) * C1 + cq * 8);
                #pragma unroll
                for (int j = 0; j < 8; ++j) {
                    float f = bf2f(v[j]);
                    s[j] += f;
                    qq[j] = fmaf(f, f, qq[j]);
                }
            }
            #pragma unroll
            for (int st = 4; st <= 32; st <<= 1) {
                #pragma unroll
                for (int j = 0; j < 8; ++j) {
                    s[j]  += __shfl_xor(s[j],  st);
                    qq[j] += __shfl_xor(qq[j], st);
                }
            }
            if (l < 4) {
                #pragma unroll
                for (int j = 0; j < 8; ++j) { redS[wave][l][j] = s[j]; redQ[wave][l][j] = qq[j]; }
            }
            __syncthreads();
            if (tid < 32) {
                int c4 = tid >> 3, j = tid & 7;
                float a = redS[0][c4][j] + redS[1][c4][j] + redS[2][c4][j] + redS[3][c4][j];
                float b = redQ[0][c4][j] + redQ[1][c4][j] + redQ[2][c4][j] + redQ[3][c4][j];
                float m = a / (float)BS;
                float var = (b - a * m) / (float)(BS - 1);
                s_mu[ss][c4 * 8 + j] = m;
                s_rs[ss][c4 * 8 + j] = rsqrtf(var + 1e-9f);
            }
            __syncthreads();
        }
    }

    // ---- Phase B: dice1 + W2 MFMA + z2 + atomic stats2 ----
    const int g = l >> 4;
    const int cB = l & 15;
    bf16x8_t bw;
    #pragma unroll
    for (int j = 0; j < 8; ++j) bw[j] = (short)f2bf(W2[(g * 8 + j) * C2 + cB]);
    const float bias = b2[cB];
    const float al = alpha1[0];

    const int cb = (l & 3) * 8;      // producer channel base
    const int srcLane = (l & 15) * 4 + g;
    for (int sq = wave * 2; sq < wave * 2 + 2; ++sq) {
        const int seqg = strip * 8 + sq;
        float sumS = 0.f, sumQ = 0.f;
        for (int t = 0; t < 16; ++t) {
            const int b0 = part * 256 + t * 16;
            const int brow = b0 + (l >> 2);
            bf16x8_t zv = *(const bf16x8_t*)(z1 + ((size_t)brow * SEQ + seqg) * C1 + cb);
            union { bf16x8_t v; int w[4]; } hp;
            #pragma unroll
            for (int j = 0; j < 8; ++j) {
                float x = bf2f(zv[j]);
                hp.v[j] = (short)f2bf(dice1(x, s_mu[sq][cb + j], s_rs[sq][cb + j], al));
            }
            union { bf16x8_t v; int w[4]; } af;
            #pragma unroll
            for (int w4 = 0; w4 < 4; ++w4) af.w[w4] = __shfl(hp.w[w4], srcLane);
            f32x4_t acc = {bias, bias, bias, bias};
            acc = __builtin_amdgcn_mfma_f32_16x16x32_bf16(af.v, bw, acc, 0, 0, 0);
            #pragma unroll
            for (int r = 0; r < 4; ++r) {
                int rb = b0 + g * 4 + r;
                z2[((size_t)rb * SEQ + seqg) * C2 + cB] = (short)f2bf(acc[r]);
                sumS += acc[r];
                sumQ = fmaf(acc[r], acc[r], sumQ);
            }
        }
        sumS += __shfl_xor(sumS, 16); sumS += __shfl_xor(sumS, 32);
        sumQ += __shfl_xor(sumQ, 16); sumQ += __shfl_xor(sumQ, 32);
        if (l < 16) {
            atomicAdd(&aS2[seqg * C2 + cB], sumS);
            atomicAdd(&aQ2[seqg * C2 + cB], sumQ);
        }
    }
}

// ---------------------------------------------------------------------------
// k3: finalize stats2 (redundant per block, L2-hot) + dice2 + attn + pooling.
// ---------------------------------------------------------------------------
__global__ __launch_bounds__(256) void k_final(const short* __restrict__ z2,
                                               const float* __restrict__ aS2,
                                               const float* __restrict__ aQ2,
                                               const float* __restrict__ alpha2,
                                               const float* __restrict__ W3,
                                               const float* __restrict__ b3,
                                               const float* __restrict__ mask,
                                               const float* __restrict__ ub,
                                               float* __restrict__ out,
                                               float* __restrict__ attns) {
    const int bs = blockIdx.x;
    const int tid = threadIdx.x;
    __shared__ float lmu[SEQ * 17];   // pad 17 to break bank aliasing
    __shared__ float lrs[SEQ * 17];
    __shared__ float s_attn[SEQ];
    __shared__ float s_w3[C2];
    __shared__ __align__(16) float4 s_pool[256];
    if (tid < C2) s_w3[tid] = W3[tid];
    for (int cell = tid; cell < SEQ * C2; cell += 256) {
        int seq = cell >> 4, c = cell & 15;
        float s = aS2[cell], qv = aQ2[cell];
        float m = s / (float)BS;
        float var = (qv - s * m) / (float)(BS - 1);
        lmu[seq * 17 + c] = m;
        lrs[seq * 17 + c] = rsqrtf(var + 1e-9f);
    }
    __syncthreads();
    if (tid < SEQ) {
        const float al = alpha2[0];
        const float bb3 = b3[0];
        bf16x8_t v0 = *(const bf16x8_t*)(z2 + ((size_t)bs * SEQ + tid) * C2);
        bf16x8_t v1 = *(const bf16x8_t*)(z2 + ((size_t)bs * SEQ + tid) * C2 + 8);
        float a = bb3;
        #pragma unroll
        for (int c = 0; c < C2; ++c) {
            float x = bf2f(c < 8 ? v0[c] : v1[c - 8]);
            a = fmaf(dice1(x, lmu[tid * 17 + c], lrs[tid * 17 + c], al), s_w3[c], a);
        }
        a *= mask[bs * SEQ + tid];
        s_attn[tid] = a;
        attns[(size_t)bs * SEQ + tid] = a;
    }
    __syncthreads();
    const int dq = tid & 15;
    const int sg = tid >> 4;
    float4 acc = {0.f, 0.f, 0.f, 0.f};
    const float4* ub4 = (const float4*)(ub + (size_t)bs * SEQ * DIM);
    for (int s = sg; s < SEQ; s += 16) {
        float a = s_attn[s];
        float4 v = ub4[s * 16 + dq];
        acc.x = fmaf(v.x, a, acc.x);
        acc.y = fmaf(v.y, a, acc.y);
        acc.z = fmaf(v.z, a, acc.z);
        acc.w = fmaf(v.w, a, acc.w);
    }
    s_pool[tid] = acc;
    for (int h = 8; h > 0; h >>= 1) {
        __syncthreads();
        if (sg < h) {
            float4 o = s_pool[tid + h * 16];
            acc.x += o.x; acc.y += o.y; acc.z += o.z; acc.w += o.w;
            s_pool[tid] = acc;
        }
    }
    if (sg == 0)
        *(float4*)(out + (size_t)bs * DIM + dq * 4) = acc;
}

extern "C" void kernel_launch(void* const* d_in, const int* in_sizes, int n_in,
                              void* d_out, int out_size, void* d_ws, size_t ws_size,
                              hipStream_t stream) {
    const float* q    = (const float*)d_in[0];
    const float* ub   = (const float*)d_in[1];
    const float* mask = (const float*)d_in[2];
    const float* W1   = (const float*)d_in[3];
    const float* b1   = (const float*)d_in[4];
    const float* a1   = (const float*)d_in[5];
    const float* W2   = (const float*)d_in[6];
    const float* b2   = (const float*)d_in[7];
    const float* a2   = (const float*)d_in[8];
    const float* W3   = (const float*)d_in[9];
    const float* b3   = (const float*)d_in[10];

    float* out   = (float*)d_out;            // (2048, 64)
    float* attns = out + (size_t)BS * DIM;   // (2048, 200, 1)

    float* ws = (float*)d_ws;
    short* z1 = (short*)ws;                              // BS*SEQ*C1 bf16 (26.2 MB)
    short* z2 = z1 + (size_t)BS * SEQ * C1;              // BS*SEQ*C2 bf16 (13.1 MB)
    float* aS2 = (float*)(z2 + (size_t)BS * SEQ * C2);   // 3200 (atomic sum)
    float* aQ2 = aS2 + SEQ * C2;                         // 3200 (atomic sumsq)

    hipMemsetAsync(aS2, 0, (size_t)SEQ * C2 * 2 * sizeof(float), stream);
    hipLaunchKernelGGL(k_gemm1, dim3(BS), dim3(256), 0, stream, q, ub, W1, b1, z1);
    hipLaunchKernelGGL(k_mlp2, dim3(25, 8), dim3(256), 0, stream,
                       z1, a1, W2, b2, z2, aS2, aQ2);
    hipLaunchKernelGGL(k_final, dim3(BS), dim3(256), 0, stream,
                       z2, aS2, aQ2, a2, W3, b3, mask, ub, out, attns);
}